// Round 1
// baseline (228.940 us; speedup 1.0000x reference)
//
#include <hip/hip_runtime.h>
#include <math.h>

#define G 16

// ---------------- Kernel A: quadrant means + 4-qubit feature sim ----------------
// One wave (64 lanes) per sample. Coalesced float4 reads; shuffle reduce; lane 0
// runs the 16-amplitude statevector sim fully unrolled in registers.
__global__ __launch_bounds__(256) void qfeat_kernel(
    const float* __restrict__ x, const float* __restrict__ params,
    float* __restrict__ qf, int B)
{
  int wave = threadIdx.x >> 6;
  int lane = threadIdx.x & 63;
  int s = blockIdx.x * 4 + wave;
  if (s >= B) return;
  const float4* xs4 = (const float4*)(x + (size_t)s * 784);
  float st0 = 0.f, st1 = 0.f, sb0 = 0.f, sb1 = 0.f;
  for (int i4 = lane; i4 < 196; i4 += 64) {
    float4 v = xs4[i4];
    int base = i4 * 4;
    int r = base / 28;
    int cb = base - r * 28;        // 0,4,...,24 — a float4 never crosses a row
    float bt = (r >= 14) ? 1.f : 0.f;
    float tp = 1.f - bt;
    float vals[4] = {v.x, v.y, v.z, v.w};
    #pragma unroll
    for (int e = 0; e < 4; ++e) {
      float val = vals[e];
      bool right = (cb + e) >= 14;
      float l = right ? 0.f : val;
      float rr = right ? val : 0.f;
      st0 = fmaf(tp, l, st0);
      st1 = fmaf(tp, rr, st1);
      sb0 = fmaf(bt, l, sb0);
      sb1 = fmaf(bt, rr, sb1);
    }
  }
  #pragma unroll
  for (int o = 32; o > 0; o >>= 1) {
    st0 += __shfl_down(st0, o, 64);
    st1 += __shfl_down(st1, o, 64);
    sb0 += __shfl_down(sb0, o, 64);
    sb1 += __shfl_down(sb1, o, 64);
  }
  if (lane == 0) {
    float sums[4] = {st0, st1, sb0, sb1};
    float cs[4], sn[4];
    #pragma unroll
    for (int q = 0; q < 4; ++q) {
      float th = 0.5f * (sums[q] * (1.f / 196.f));
      __sincosf(th, &sn[q], &cs[q]);
    }
    // |psi> after RY layer: real product state. idx bit layout: qubit q -> bit (3-q).
    float re[16], im[16];
    #pragma unroll
    for (int idx = 0; idx < 16; ++idx) {
      float a = ((idx >> 3) & 1) ? sn[0] : cs[0];
      a *= ((idx >> 2) & 1) ? sn[1] : cs[1];
      a *= ((idx >> 1) & 1) ? sn[2] : cs[2];
      a *= (idx & 1) ? sn[3] : cs[3];
      re[idx] = a;
      im[idx] = 0.f;
    }
    // RZ(params[q]) on q, then CNOT(q, (q+1)%4), q = 0..3
    #pragma unroll
    for (int q = 0; q < 4; ++q) {
      float hp = 0.5f * params[q];
      float cp, sp;
      __sincosf(hp, &sp, &cp);
      int qb = 3 - q;
      #pragma unroll
      for (int idx = 0; idx < 16; ++idx) {
        float sg = ((idx >> qb) & 1) ? sp : -sp;  // exp(+-i p/2)
        float r0 = re[idx], i0 = im[idx];
        re[idx] = r0 * cp - i0 * sg;
        im[idx] = r0 * sg + i0 * cp;
      }
      int cm = 1 << qb;
      int tm = 1 << (3 - ((q + 1) & 3));
      #pragma unroll
      for (int idx = 0; idx < 16; ++idx) {
        if ((idx & cm) && !(idx & tm)) {
          int j = idx | tm;
          float tr = re[idx]; re[idx] = re[j]; re[j] = tr;
          float ti = im[idx]; im[idx] = im[j]; im[j] = ti;
        }
      }
    }
    #pragma unroll
    for (int q = 0; q < 4; ++q) {
      int qb = 3 - q;
      float z = 0.f;
      #pragma unroll
      for (int idx = 0; idx < 16; ++idx) {
        float p = re[idx] * re[idx] + im[idx] * im[idx];
        z += ((idx >> qb) & 1) ? -p : p;
      }
      qf[s * 4 + q] = z;
    }
  }
}

// ---------------- Kernel B: latent -> fc -> deconv1 -> deconv2 -> sigmoid ----------------
// One block per G=16 samples. latent in LDS (stride 228: 16B-aligned float4 rows,
// only 2-way bank aliasing which is free). fc matvec uses 2-sample x 4-output
// register tiling: each LDS b128 read feeds 16 FMAs. w_fc rows are wave-broadcast
// global reads (L2 resident). Deconvs fused per 2x2 output block, float2 stores.
__global__ __launch_bounds__(256) void decoder_kernel(
    const float* __restrict__ qf,
    const float* __restrict__ w_lat, const float* __restrict__ b_lat,
    const float* __restrict__ w_fc, const float* __restrict__ b_fc,
    const float* __restrict__ w_d1, const float* __restrict__ b_d1,
    const float* __restrict__ w_d2, const float* __restrict__ b_d2,
    float* __restrict__ out, int B)
{
  __shared__ __align__(16) float lat[G * 228];
  __shared__ __align__(16) float hbuf[G * 396];
  __shared__ float qfs[G * 4];
  __shared__ float wd1[128];
  __shared__ float wd2[16];
  __shared__ float bd1[4];
  const int t = threadIdx.x;
  const int s0g = blockIdx.x * G;

  if (t < 64) qfs[t] = qf[s0g * 4 + t];
  else if (t < 192) wd1[t - 64] = w_d1[t - 64];
  else if (t < 208) wd2[t - 192] = w_d2[t - 192];
  else if (t < 212) bd1[t - 208] = b_d1[t - 208];
  __syncthreads();

  // Phase 2: latent[s][j] = relu(qf[s] . w_lat[j] + b_lat[j]), 16x224
  for (int v = t; v < G * 224; v += 256) {
    int s = v / 224;
    int j = v - s * 224;
    float4 w = *(const float4*)(w_lat + j * 4);
    float a = b_lat[j];
    a = fmaf(qfs[s * 4 + 0], w.x, a);
    a = fmaf(qfs[s * 4 + 1], w.y, a);
    a = fmaf(qfs[s * 4 + 2], w.z, a);
    a = fmaf(qfs[s * 4 + 3], w.w, a);
    lat[s * 228 + j] = fmaxf(a, 0.f);
  }
  __syncthreads();

  // Phase 3: h[s][j] = relu(latent[s] . w_fc[j] + b_fc[j]), 16x392
  // 2 samples x 4 outputs per thread-task.
  {
    const int sp = t & 7;      // sample pair 0..7
    const int jq = t >> 3;     // j-quad slot 0..31
    const int sA = sp * 2, sB = sA + 1;
    const float4* la = (const float4*)(lat + sA * 228);
    const float4* lb = (const float4*)(lat + sB * 228);
    for (int q4 = jq; q4 < 98; q4 += 32) {
      int j0 = q4 * 4;
      const float4* w0 = (const float4*)(w_fc + (size_t)(j0 + 0) * 224);
      const float4* w1 = (const float4*)(w_fc + (size_t)(j0 + 1) * 224);
      const float4* w2 = (const float4*)(w_fc + (size_t)(j0 + 2) * 224);
      const float4* w3 = (const float4*)(w_fc + (size_t)(j0 + 3) * 224);
      float a0 = 0, a1 = 0, a2 = 0, a3 = 0;
      float b0 = 0, b1 = 0, b2 = 0, b3 = 0;
      #pragma unroll 2
      for (int k = 0; k < 56; ++k) {
        float4 va = la[k], vb = lb[k];
        float4 u0 = w0[k], u1 = w1[k], u2 = w2[k], u3 = w3[k];
        a0 = fmaf(va.x, u0.x, fmaf(va.y, u0.y, fmaf(va.z, u0.z, fmaf(va.w, u0.w, a0))));
        a1 = fmaf(va.x, u1.x, fmaf(va.y, u1.y, fmaf(va.z, u1.z, fmaf(va.w, u1.w, a1))));
        a2 = fmaf(va.x, u2.x, fmaf(va.y, u2.y, fmaf(va.z, u2.z, fmaf(va.w, u2.w, a2))));
        a3 = fmaf(va.x, u3.x, fmaf(va.y, u3.y, fmaf(va.z, u3.z, fmaf(va.w, u3.w, a3))));
        b0 = fmaf(vb.x, u0.x, fmaf(vb.y, u0.y, fmaf(vb.z, u0.z, fmaf(vb.w, u0.w, b0))));
        b1 = fmaf(vb.x, u1.x, fmaf(vb.y, u1.y, fmaf(vb.z, u1.z, fmaf(vb.w, u1.w, b1))));
        b2 = fmaf(vb.x, u2.x, fmaf(vb.y, u2.y, fmaf(vb.z, u2.z, fmaf(vb.w, u2.w, b2))));
        b3 = fmaf(vb.x, u3.x, fmaf(vb.y, u3.y, fmaf(vb.z, u3.z, fmaf(vb.w, u3.w, b3))));
      }
      float f0 = b_fc[j0 + 0], f1 = b_fc[j0 + 1], f2 = b_fc[j0 + 2], f3 = b_fc[j0 + 3];
      hbuf[sA * 396 + j0 + 0] = fmaxf(a0 + f0, 0.f);
      hbuf[sA * 396 + j0 + 1] = fmaxf(a1 + f1, 0.f);
      hbuf[sA * 396 + j0 + 2] = fmaxf(a2 + f2, 0.f);
      hbuf[sA * 396 + j0 + 3] = fmaxf(a3 + f3, 0.f);
      hbuf[sB * 396 + j0 + 0] = fmaxf(b0 + f0, 0.f);
      hbuf[sB * 396 + j0 + 1] = fmaxf(b1 + f1, 0.f);
      hbuf[sB * 396 + j0 + 2] = fmaxf(b2 + f2, 0.f);
      hbuf[sB * 396 + j0 + 3] = fmaxf(b3 + f3, 0.f);
    }
  }
  __syncthreads();

  // Phase 4: deconv1(8->4, k=s=2) + relu + deconv2(4->1, k=s=2) + sigmoid.
  // One task per (sample, Y, X) with Y,X in 14x14 of the intermediate map;
  // emits the 2x2 final pixels as two float2 stores.
  const float bd2v = b_d2[0];
  for (int v = t; v < G * 196; v += 256) {
    int s = v / 196;
    int p = v - s * 196;
    int Y = p / 14;
    int X = p - Y * 14;
    int y = Y >> 1, ey = Y & 1, xx = X >> 1, ex = X & 1;
    const float* hs = hbuf + s * 396 + y * 7 + xx;
    float hv[8];
    #pragma unroll
    for (int ci = 0; ci < 8; ++ci) hv[ci] = hs[ci * 49];
    float o1[4];
    #pragma unroll
    for (int co = 0; co < 4; ++co) {
      float a = bd1[co];
      #pragma unroll
      for (int ci = 0; ci < 8; ++ci)
        a = fmaf(hv[ci], wd1[ci * 16 + co * 4 + ey * 2 + ex], a);
      o1[co] = fmaxf(a, 0.f);
    }
    size_t basep = (size_t)(s0g + s) * 784;
    #pragma unroll
    for (int dy = 0; dy < 2; ++dy) {
      float v0 = bd2v, v1 = bd2v;
      #pragma unroll
      for (int co = 0; co < 4; ++co) {
        v0 = fmaf(o1[co], wd2[co * 4 + dy * 2 + 0], v0);
        v1 = fmaf(o1[co], wd2[co * 4 + dy * 2 + 1], v1);
      }
      float2 o;
      o.x = 1.f / (1.f + __expf(-v0));
      o.y = 1.f / (1.f + __expf(-v1));
      *(float2*)(out + basep + (size_t)(2 * Y + dy) * 28 + 2 * X) = o;
    }
  }
}

extern "C" void kernel_launch(void* const* d_in, const int* in_sizes, int n_in,
                              void* d_out, int out_size, void* d_ws, size_t ws_size,
                              hipStream_t stream) {
  const float* x          = (const float*)d_in[0];
  const float* var_params = (const float*)d_in[1];
  const float* w_lat      = (const float*)d_in[2];
  const float* b_lat      = (const float*)d_in[3];
  const float* w_fc       = (const float*)d_in[4];
  const float* b_fc       = (const float*)d_in[5];
  const float* w_d1       = (const float*)d_in[6];
  const float* b_d1       = (const float*)d_in[7];
  const float* w_d2       = (const float*)d_in[8];
  const float* b_d2       = (const float*)d_in[9];
  float* out = (float*)d_out;
  float* qf  = (float*)d_ws;   // B*4 floats of scratch

  int B = in_sizes[0] / 784;
  qfeat_kernel<<<(B + 3) / 4, 256, 0, stream>>>(x, var_params, qf, B);
  decoder_kernel<<<(B + G - 1) / G, 256, 0, stream>>>(
      qf, w_lat, b_lat, w_fc, b_fc, w_d1, b_d1, w_d2, b_d2, out, B);
}

// Round 2
// 142.778 us; speedup vs baseline: 1.6035x; 1.6035x over previous
//
#include <hip/hip_runtime.h>
#include <math.h>

#define G 16
#define HS 396          // hbuf row stride (floats)
#define LSTR 232        // latb row stride (bf16): 464B, 16B-aligned, 2-way-bank only

typedef __attribute__((ext_vector_type(8))) __bf16 bf16x8;
typedef __attribute__((ext_vector_type(4))) float f32x4;

// ---------------- Kernel W: swizzle w_fc (392x224 fp32) into bf16 MFMA B-fragments ----------
// Layout: wb[((tile*7 + kt)*64 + lane)*8 + j] = bf16(w_fc[n][k]), n = tile*16 + (lane&15),
// k = kt*32 + (lane>>4)*8 + j.  Tiles 0..24 (N padded 392->400 with zeros).
__global__ void wconv_kernel(const float* __restrict__ w_fc, __bf16* __restrict__ wb) {
  int tile = blockIdx.x;      // 0..24
  int kt   = blockIdx.y;      // 0..6
  int lane = threadIdx.x;     // 0..63
  int n  = tile * 16 + (lane & 15);
  int k0 = kt * 32 + (lane >> 4) * 8;
  bf16x8 v;
  if (n < 392) {
    const float* src = w_fc + (size_t)n * 224 + k0;
    float4 f0 = *(const float4*)(src);
    float4 f1 = *(const float4*)(src + 4);
    v[0] = (__bf16)f0.x; v[1] = (__bf16)f0.y; v[2] = (__bf16)f0.z; v[3] = (__bf16)f0.w;
    v[4] = (__bf16)f1.x; v[5] = (__bf16)f1.y; v[6] = (__bf16)f1.z; v[7] = (__bf16)f1.w;
  } else {
    #pragma unroll
    for (int j = 0; j < 8; ++j) v[j] = (__bf16)0.f;
  }
  *(bf16x8*)(wb + ((size_t)(tile * 7 + kt) * 64 + lane) * 8) = v;
}

// ---------------- Kernel A1: quadrant means (pure streaming, no serial tail) ----------------
// One wave per sample; coalesced float4 reads; shuffle reduce; lane 0 writes 4 means.
__global__ __launch_bounds__(256) void qsum_kernel(
    const float* __restrict__ x, float* __restrict__ angles, int B)
{
  int wave = threadIdx.x >> 6;
  int lane = threadIdx.x & 63;
  int s = blockIdx.x * 4 + wave;
  if (s >= B) return;
  const float4* xs4 = (const float4*)(x + (size_t)s * 784);
  float st0 = 0.f, st1 = 0.f, sb0 = 0.f, sb1 = 0.f;
  for (int i4 = lane; i4 < 196; i4 += 64) {
    float4 v = xs4[i4];
    int base = i4 * 4;
    int r = base / 28;
    int cb = base - r * 28;        // a float4 never crosses a row (28 % 4 == 0)
    float bt = (r >= 14) ? 1.f : 0.f;
    float tp = 1.f - bt;
    float vals[4] = {v.x, v.y, v.z, v.w};
    #pragma unroll
    for (int e = 0; e < 4; ++e) {
      float val = vals[e];
      bool right = (cb + e) >= 14;
      float l = right ? 0.f : val;
      float rr = right ? val : 0.f;
      st0 = fmaf(tp, l, st0);
      st1 = fmaf(tp, rr, st1);
      sb0 = fmaf(bt, l, sb0);
      sb1 = fmaf(bt, rr, sb1);
    }
  }
  #pragma unroll
  for (int o = 32; o > 0; o >>= 1) {
    st0 += __shfl_down(st0, o, 64);
    st1 += __shfl_down(st1, o, 64);
    sb0 += __shfl_down(sb0, o, 64);
    sb1 += __shfl_down(sb1, o, 64);
  }
  if (lane == 0) {
    const float inv = 1.f / 196.f;
    float4 o;
    o.x = st0 * inv; o.y = st1 * inv; o.z = sb0 * inv; o.w = sb1 * inv;
    *(float4*)(angles + 4 * s) = o;
  }
}

// ---------------- Kernel A2: 4-qubit sim, one THREAD per sample (all lanes active) ----------
// In/out aliased: reads 4 means, writes 4 <Z_q> features to the same slot.
__global__ __launch_bounds__(256) void qsim_kernel(
    const float* __restrict__ params, float* __restrict__ qfa, int B)
{
  int s = blockIdx.x * 256 + threadIdx.x;
  if (s >= B) return;
  float4 mn = *(const float4*)(qfa + 4 * s);
  float means[4] = {mn.x, mn.y, mn.z, mn.w};
  float cs[4], sn[4];
  #pragma unroll
  for (int q = 0; q < 4; ++q) {
    float th = 0.5f * means[q];
    sn[q] = __sinf(th);
    cs[q] = __cosf(th);
  }
  // |psi> after RY layer: real product state; qubit q -> bit (3-q).
  float re[16], im[16];
  #pragma unroll
  for (int idx = 0; idx < 16; ++idx) {
    float a = ((idx >> 3) & 1) ? sn[0] : cs[0];
    a *= ((idx >> 2) & 1) ? sn[1] : cs[1];
    a *= ((idx >> 1) & 1) ? sn[2] : cs[2];
    a *= (idx & 1) ? sn[3] : cs[3];
    re[idx] = a;
    im[idx] = 0.f;
  }
  // RZ(params[q]) on q, then CNOT(q, (q+1)%4)
  #pragma unroll
  for (int q = 0; q < 4; ++q) {
    float hp = 0.5f * params[q];
    float sp = __sinf(hp), cp = __cosf(hp);
    int qb = 3 - q;
    #pragma unroll
    for (int idx = 0; idx < 16; ++idx) {
      float sg = ((idx >> qb) & 1) ? sp : -sp;   // exp(+-i p/2)
      float r0 = re[idx], i0 = im[idx];
      re[idx] = r0 * cp - i0 * sg;
      im[idx] = r0 * sg + i0 * cp;
    }
    int cm = 1 << qb;
    int tm = 1 << (3 - ((q + 1) & 3));
    #pragma unroll
    for (int idx = 0; idx < 16; ++idx) {
      if ((idx & cm) && !(idx & tm)) {
        int j = idx | tm;
        float tr = re[idx]; re[idx] = re[j]; re[j] = tr;
        float ti = im[idx]; im[idx] = im[j]; im[j] = ti;
      }
    }
  }
  float z[4];
  #pragma unroll
  for (int q = 0; q < 4; ++q) {
    int qb = 3 - q;
    float acc = 0.f;
    #pragma unroll
    for (int idx = 0; idx < 16; ++idx) {
      float p = re[idx] * re[idx] + im[idx] * im[idx];
      acc += ((idx >> qb) & 1) ? -p : p;
    }
    z[q] = acc;
  }
  float4 o; o.x = z[0]; o.y = z[1]; o.z = z[2]; o.w = z[3];
  *(float4*)(qfa + 4 * s) = o;
}

// ---------------- Kernel B: latent -> MFMA fc -> deconv1 -> deconv2 -> sigmoid ----------------
// One block per 16 samples. Phase 3 is 25x7 mfma_f32_16x16x32_bf16 per block:
// A = latent (16x224 bf16 in LDS, A[m=lane&15][k=(lane>>4)*8+j]); B streamed from the
// pre-swizzled wb buffer (one coalesced dwordx4 per mfma, L2-hot); C/D col=lane&15,
// row=(lane>>4)*4+reg.
__global__ __launch_bounds__(256) void decoder_kernel(
    const float* __restrict__ qf, const __bf16* __restrict__ wb,
    const float* __restrict__ w_lat, const float* __restrict__ b_lat,
    const float* __restrict__ b_fc,
    const float* __restrict__ w_d1, const float* __restrict__ b_d1,
    const float* __restrict__ w_d2, const float* __restrict__ b_d2,
    float* __restrict__ out, int B)
{
  __shared__ __align__(16) __bf16 latb[G * LSTR];
  __shared__ __align__(16) float hbuf[G * HS];
  __shared__ float qfs[G * 4];
  __shared__ float wd1[128];
  __shared__ float wd2[16];
  __shared__ float bd1[4];
  const int t = threadIdx.x;
  const int s0g = blockIdx.x * G;

  if (t < 64) qfs[t] = qf[s0g * 4 + t];
  else if (t < 192) wd1[t - 64] = w_d1[t - 64];
  else if (t < 208) wd2[t - 192] = w_d2[t - 192];
  else if (t < 212) bd1[t - 208] = b_d1[t - 208];
  __syncthreads();

  // Phase 2: latent[s][j] = relu(qf[s] . w_lat[j] + b_lat[j]) -> bf16 LDS
  for (int v = t; v < G * 224; v += 256) {
    int s = v / 224;
    int j = v - s * 224;
    float4 w = *(const float4*)(w_lat + j * 4);
    float a = b_lat[j];
    a = fmaf(qfs[s * 4 + 0], w.x, a);
    a = fmaf(qfs[s * 4 + 1], w.y, a);
    a = fmaf(qfs[s * 4 + 2], w.z, a);
    a = fmaf(qfs[s * 4 + 3], w.w, a);
    latb[s * LSTR + j] = (__bf16)fmaxf(a, 0.f);
  }
  __syncthreads();

  // Phase 3: MFMA. wave wv handles N-tiles wv, wv+4, ...
  {
    const int wv = t >> 6;
    const int lane = t & 63;
    const int m = lane & 15;       // A-row (sample) AND B/D-col (n) index
    const int kq = lane >> 4;      // k-quad
    const __bf16* arow = latb + m * LSTR + kq * 8;
    for (int tile = wv; tile < 25; tile += 4) {
      f32x4 acc = {0.f, 0.f, 0.f, 0.f};
      const bf16x8* bp = (const bf16x8*)(wb + ((size_t)(tile * 7) * 64 + lane) * 8);
      #pragma unroll
      for (int kt = 0; kt < 7; ++kt) {
        bf16x8 a = *(const bf16x8*)(arow + kt * 32);
        bf16x8 b = bp[kt * 64];
        acc = __builtin_amdgcn_mfma_f32_16x16x32_bf16(a, b, acc, 0, 0, 0);
      }
      int j = tile * 16 + m;
      if (j < 392) {
        float bf = b_fc[j];
        #pragma unroll
        for (int r = 0; r < 4; ++r)
          hbuf[(kq * 4 + r) * HS + j] = fmaxf(acc[r] + bf, 0.f);
      }
    }
  }
  __syncthreads();

  // Phase 4: deconv1(8->4, k=s=2) + relu + deconv2(4->1, k=s=2) + sigmoid.
  const float bd2v = b_d2[0];
  for (int v = t; v < G * 196; v += 256) {
    int s = v / 196;
    int p = v - s * 196;
    int Y = p / 14;
    int X = p - Y * 14;
    int y = Y >> 1, ey = Y & 1, xx = X >> 1, ex = X & 1;
    const float* hs = hbuf + s * HS + y * 7 + xx;
    float hv[8];
    #pragma unroll
    for (int ci = 0; ci < 8; ++ci) hv[ci] = hs[ci * 49];
    float o1[4];
    #pragma unroll
    for (int co = 0; co < 4; ++co) {
      float a = bd1[co];
      #pragma unroll
      for (int ci = 0; ci < 8; ++ci)
        a = fmaf(hv[ci], wd1[ci * 16 + co * 4 + ey * 2 + ex], a);
      o1[co] = fmaxf(a, 0.f);
    }
    size_t basep = (size_t)(s0g + s) * 784;
    #pragma unroll
    for (int dy = 0; dy < 2; ++dy) {
      float v0 = bd2v, v1 = bd2v;
      #pragma unroll
      for (int co = 0; co < 4; ++co) {
        v0 = fmaf(o1[co], wd2[co * 4 + dy * 2 + 0], v0);
        v1 = fmaf(o1[co], wd2[co * 4 + dy * 2 + 1], v1);
      }
      float2 o;
      o.x = 1.f / (1.f + __expf(-v0));
      o.y = 1.f / (1.f + __expf(-v1));
      *(float2*)(out + basep + (size_t)(2 * Y + dy) * 28 + 2 * X) = o;
    }
  }
}

extern "C" void kernel_launch(void* const* d_in, const int* in_sizes, int n_in,
                              void* d_out, int out_size, void* d_ws, size_t ws_size,
                              hipStream_t stream) {
  const float* x          = (const float*)d_in[0];
  const float* var_params = (const float*)d_in[1];
  const float* w_lat      = (const float*)d_in[2];
  const float* b_lat      = (const float*)d_in[3];
  const float* w_fc       = (const float*)d_in[4];
  const float* b_fc       = (const float*)d_in[5];
  const float* w_d1       = (const float*)d_in[6];
  const float* b_d1       = (const float*)d_in[7];
  const float* w_d2       = (const float*)d_in[8];
  const float* b_d2       = (const float*)d_in[9];
  float* out = (float*)d_out;

  // ws layout: [0, 179200)  bf16-swizzled w_fc fragments
  //            [262144, 524288)  angles -> (aliased, overwritten in-place) qfeatures
  __bf16* wb   = (__bf16*)d_ws;
  float* qfa   = (float*)((char*)d_ws + 262144);

  int B = in_sizes[0] / 784;
  wconv_kernel<<<dim3(25, 7), 64, 0, stream>>>(w_fc, wb);
  qsum_kernel<<<(B + 3) / 4, 256, 0, stream>>>(x, qfa, B);
  qsim_kernel<<<(B + 255) / 256, 256, 0, stream>>>(var_params, qfa, B);
  decoder_kernel<<<(B + G - 1) / G, 256, 0, stream>>>(
      qfa, wb, w_lat, b_lat, b_fc, w_d1, b_d1, w_d2, b_d2, out, B);
}